// Round 4
// baseline (157.965 us; speedup 1.0000x reference)
//
#include <hip/hip_runtime.h>

#define BATCH 4096
#define SEQT  512
#define HID   32
#define CH    32                       // timestep chunk held in LDS history
#define RSTRIDE 20                     // dwords per t-row (80 B, 16B-aligned, bank-spread)
#define SEQSTRIDE (CH * RSTRIDE + 4)   // 644 dwords per sequence slice

typedef _Float16 f16;
typedef _Float16 h2 __attribute__((ext_vector_type(2)));

#if __has_builtin(__builtin_amdgcn_fdot2)
#define FDOT2(a, b, c) __builtin_amdgcn_fdot2((a), (b), (c), false)
#else
#define FDOT2(a, b, c) fmaf((float)(a)[1], (float)(b)[1], fmaf((float)(a)[0], (float)(b)[0], (c)))
#endif

#if __has_builtin(__builtin_amdgcn_exp2f)
#define FAST_EXP2(x) __builtin_amdgcn_exp2f(x)
#else
#define FAST_EXP2(x) exp2f(x)
#endif
#if __has_builtin(__builtin_amdgcn_rcpf)
#define FAST_RCP(x) __builtin_amdgcn_rcpf(x)
#else
#define FAST_RCP(x) (1.0f / (x))
#endif

// rotate-by-i within each 16-lane row. Direction does not matter for
// correctness: weight indices are derived through the SAME primitive.
#if __has_builtin(__builtin_amdgcn_update_dpp)
#define ROT16(v, i) __builtin_amdgcn_update_dpp(0, (v), 0x120 + (i), 0xF, 0xF, true)
#else
#define ROT16(v, i) __shfl((v), (int)((threadIdx.x & ~15u) | ((threadIdx.x + (i)) & 15u)), 64)
#endif

#define GATHER15(dst, src) \
    dst[1]  = ROT16(src, 1);  dst[2]  = ROT16(src, 2);  dst[3]  = ROT16(src, 3);  \
    dst[4]  = ROT16(src, 4);  dst[5]  = ROT16(src, 5);  dst[6]  = ROT16(src, 6);  \
    dst[7]  = ROT16(src, 7);  dst[8]  = ROT16(src, 8);  dst[9]  = ROT16(src, 9);  \
    dst[10] = ROT16(src, 10); dst[11] = ROT16(src, 11); dst[12] = ROT16(src, 12); \
    dst[13] = ROT16(src, 13); dst[14] = ROT16(src, 14); dst[15] = ROT16(src, 15);

#define BCI(x) __builtin_bit_cast(h2, (x))   // int  -> 2 x f16
#define BCF(x) __builtin_bit_cast(h2, (x))   // f32  -> 2 x f16 (bit pattern)

static __device__ __forceinline__ int packh(float a, float b) {
    h2 v = {(f16)a, (f16)b};                 // RTN converts
    return __builtin_bit_cast(int, v);
}

// One wave = 4 sequences, one sequence per 16-lane DPP row.
// Lane l of a row computes h[l] and h[l+16]; after tanh it packs them into
// one dword d0. The full previous-h vector is all-gathered IN REGISTERS via
// 15 row_ror DPP movs (VALU pipe, depth 1) -- the recurrence chain touches
// no LDS at all. 32 v_dot2_f32_f16 per lane compute both k-sums. Output dot
// is deferred: d0 is spilled to a padded LDS history (1 ds_write_b32/step,
// off-chain) and a chunk-end pass computes 32 outputs/seq with conflict-free
// b128 reads + fdot2, storing coalesced to global.
__global__ __launch_bounds__(64) void rnn_kernel(
    const float* __restrict__ x,      // [B, T]
    const float* __restrict__ h0,     // [B, H]
    const float* __restrict__ W_ih,   // [H]
    const float* __restrict__ b_ih,   // [H]
    const float* __restrict__ W_hh,   // [H, H] row-major
    const float* __restrict__ b_hh,   // [H]
    const float* __restrict__ W_out,  // [H]
    const float* __restrict__ b_out,  // [1]
    float* __restrict__ out)          // [B*T] outs, then [B*H] hT
{
    const int lane = threadIdx.x & 63;
    const int row  = lane >> 4;       // sequence-in-wave (0..3)
    const int l    = lane & 15;       // lane-in-row = hidden index base
    const int bs0  = blockIdx.x * 4;  // first sequence of this wave
    const int bseq = bs0 + row;

    __shared__ __align__(16) float hist[4 * SEQSTRIDE];  // ~10.1 KB
    __shared__ float xbuf[4 * CH];

    // ---- source-lane indices through the SAME rotation primitive ----
    int idx[16];
    idx[0] = l;
    GATHER15(idx, l);

    // ---- per-lane weights: Wr0 for output l, Wr1 for output l+16 ----
    // Wr*[i] pairs (W[j][s_i], W[j][s_i+16]) to match gathered d_i order.
    h2 Wr0[16], Wr1[16];
    #pragma unroll
    for (int i = 0; i < 16; ++i) {
        const int s = idx[i];
        Wr0[i] = h2{(f16)W_hh[l * HID + s],        (f16)W_hh[l * HID + s + 16]};
        Wr1[i] = h2{(f16)W_hh[(l + 16) * HID + s], (f16)W_hh[(l + 16) * HID + s + 16]};
    }
    // output weights, pair (Wo[i], Wo[i+16]) -- lane-uniform
    h2 Wo[16];
    #pragma unroll
    for (int i = 0; i < 16; ++i)
        Wo[i] = h2{(f16)W_out[i], (f16)W_out[i + 16]};

    const float wih0  = W_ih[l];
    const float wih1  = W_ih[l + 16];
    const float bias0 = b_ih[l] + b_hh[l];
    const float bias1 = b_ih[l + 16] + b_hh[l + 16];
    const float bout  = b_out[0];

    // seed packed h_{-1}
    int d0 = packh(h0[(size_t)bseq * HID + l], h0[(size_t)bseq * HID + l + 16]);

    const float* xg = x + (size_t)bs0 * SEQT;
    float*       og = out + (size_t)bs0 * SEQT;

    for (int tc = 0; tc < SEQT; tc += CH) {
        // ---- stage x chunk for all 4 sequences (2 coalesced rounds) ----
        xbuf[lane]      = xg[(size_t)(lane >> 5) * SEQT + tc + (lane & 31)];
        xbuf[lane + 64] = xg[(size_t)((lane >> 5) + 2) * SEQT + tc + (lane & 31)];
        __builtin_amdgcn_wave_barrier();

        float xc = xbuf[row * CH];

        #pragma unroll 8
        for (int t2 = 0; t2 < CH; ++t2) {
            // in-register all-gather of previous h (15 DPP movs, depth 1)
            int d[16];
            d[0] = d0;
            GATHER15(d, d0);

            const float xn = xbuf[row * CH + ((t2 + 1) & (CH - 1))];  // off-chain

            // 32 fdot2 in 8 independent chains (depth 4 each)
            float a00 = fmaf(xc, wih0, bias0);
            float a01 = 0.0f, a02 = 0.0f, a03 = 0.0f;
            float a10 = fmaf(xc, wih1, bias1);
            float a11 = 0.0f, a12 = 0.0f, a13 = 0.0f;
            #pragma unroll
            for (int i = 0; i < 4; ++i) {
                a00 = FDOT2(BCI(d[4 * i + 0]), Wr0[4 * i + 0], a00);
                a10 = FDOT2(BCI(d[4 * i + 0]), Wr1[4 * i + 0], a10);
                a01 = FDOT2(BCI(d[4 * i + 1]), Wr0[4 * i + 1], a01);
                a11 = FDOT2(BCI(d[4 * i + 1]), Wr1[4 * i + 1], a11);
                a02 = FDOT2(BCI(d[4 * i + 2]), Wr0[4 * i + 2], a02);
                a12 = FDOT2(BCI(d[4 * i + 2]), Wr1[4 * i + 2], a12);
                a03 = FDOT2(BCI(d[4 * i + 3]), Wr0[4 * i + 3], a03);
                a13 = FDOT2(BCI(d[4 * i + 3]), Wr1[4 * i + 3], a13);
            }
            const float p0 = (a00 + a01) + (a02 + a03);
            const float p1 = (a10 + a11) + (a12 + a13);

            // tanh(p) = 1 - 2/(exp2(2p*log2e)+1); saturates correctly
            const float e0  = FAST_EXP2(p0 * 2.8853900817779268f);
            const float e1  = FAST_EXP2(p1 * 2.8853900817779268f);
            const float hn0 = fmaf(-2.0f, FAST_RCP(e0 + 1.0f), 1.0f);
            const float hn1 = fmaf(-2.0f, FAST_RCP(e1 + 1.0f), 1.0f);

            d0 = packh(hn0, hn1);

            // spill packed h to history (off the recurrence chain)
            hist[row * SEQSTRIDE + t2 * RSTRIDE + l] = __builtin_bit_cast(float, d0);
            __builtin_amdgcn_wave_barrier();

            xc = xn;
        }

        // ---- chunk-end output pass: 2 outputs per lane, conflict-free ----
        #pragma unroll
        for (int c = 0; c < 2; ++c) {
            const int io  = lane + 64 * c;   // 0..127 -> (seq, t)
            const int seq = io >> 5;
            const int t   = io & 31;
            const float4* hp =
                reinterpret_cast<const float4*>(&hist[seq * SEQSTRIDE + t * RSTRIDE]);
            const float4 q0 = hp[0], q1 = hp[1], q2 = hp[2], q3 = hp[3];
            float o0 = FDOT2(BCF(q0.x), Wo[0],  bout);
            float o1 = FDOT2(BCF(q0.y), Wo[1],  0.0f);
            float o2 = FDOT2(BCF(q0.z), Wo[2],  0.0f);
            float o3 = FDOT2(BCF(q0.w), Wo[3],  0.0f);
            o0 = FDOT2(BCF(q1.x), Wo[4],  o0);
            o1 = FDOT2(BCF(q1.y), Wo[5],  o1);
            o2 = FDOT2(BCF(q1.z), Wo[6],  o2);
            o3 = FDOT2(BCF(q1.w), Wo[7],  o3);
            o0 = FDOT2(BCF(q2.x), Wo[8],  o0);
            o1 = FDOT2(BCF(q2.y), Wo[9],  o1);
            o2 = FDOT2(BCF(q2.z), Wo[10], o2);
            o3 = FDOT2(BCF(q2.w), Wo[11], o3);
            o0 = FDOT2(BCF(q3.x), Wo[12], o0);
            o1 = FDOT2(BCF(q3.y), Wo[13], o1);
            o2 = FDOT2(BCF(q3.z), Wo[14], o2);
            o3 = FDOT2(BCF(q3.w), Wo[15], o3);
            og[(size_t)seq * SEQT + tc + t] = (o0 + o1) + (o2 + o3);
        }
        __builtin_amdgcn_wave_barrier();
    }

    // final hidden state [1, B, H]
    const h2 hf = BCI(d0);
    out[(size_t)BATCH * SEQT + (size_t)bseq * HID + l]      = (float)hf[0];
    out[(size_t)BATCH * SEQT + (size_t)bseq * HID + l + 16] = (float)hf[1];
}

extern "C" void kernel_launch(void* const* d_in, const int* in_sizes, int n_in,
                              void* d_out, int out_size, void* d_ws, size_t ws_size,
                              hipStream_t stream) {
    const float* x     = (const float*)d_in[0];
    const float* h0    = (const float*)d_in[1];
    const float* W_ih  = (const float*)d_in[2];
    const float* b_ih  = (const float*)d_in[3];
    const float* W_hh  = (const float*)d_in[4];
    const float* b_hh  = (const float*)d_in[5];
    const float* W_out = (const float*)d_in[6];
    const float* b_out = (const float*)d_in[7];
    float* outp = (float*)d_out;

    dim3 grid(BATCH / 4);   // 1024 waves, 4 sequences each -> 1 wave/SIMD
    dim3 block(64);
    hipLaunchKernelGGL(rnn_kernel, grid, block, 0, stream,
                       x, h0, W_ih, b_ih, W_hh, b_hh, W_out, b_out, outp);
}